// Round 1
// baseline (1499.887 us; speedup 1.0000x reference)
//
#include <hip/hip_runtime.h>

#define EPSILON 0.01f

// ---------------------------------------------------------------------------
// R1 theory: pass-1/2 scatter atomics ping-pong cache lines across the 8
// non-coherent XCD L2s (WRITE_SIZE 100MB == 12.8M atomics x 8B to fabric).
// Fix: per-XCD accumulator replicas selected by blockIdx % K (K<=8), reduced
// by cheap node-grid kernels. Also: 1 thread/edge (was 4 lanes/edge) -- no
// shuffles, 4x fewer waves, coalesced 64B boo load per thread.
// ---------------------------------------------------------------------------

// Pass 1: msg_t[i] = sum_j B[e][j][i] * x[row[e]][j]; atomic-add into the
// blockIdx%K replica of ATx at col[e].
__global__ void __launch_bounds__(256) spmvt_kernel(
    const float4* __restrict__ boo,   // [E*4] rows of B
    const int* __restrict__ row,
    const int* __restrict__ col,
    const float4* __restrict__ x4,    // [N]
    float* __restrict__ atx,          // [K * N*4], pre-zeroed
    long long n4,                     // N*4 (replica stride in floats)
    int nrep,                         // K (power of 2)
    long long E)
{
    long long e = (long long)blockIdx.x * blockDim.x + threadIdx.x;
    if (e >= E) return;

    const float4* B = boo + e * 4;
    float4 b0 = B[0], b1 = B[1], b2 = B[2], b3 = B[3];
    int r = row[e];
    int c = col[e];
    float4 xv = x4[r];

    // B^T x  (column i of B dotted with x)
    float4 m;
    m.x = b0.x*xv.x + b1.x*xv.y + b2.x*xv.z + b3.x*xv.w;
    m.y = b0.y*xv.x + b1.y*xv.y + b2.y*xv.z + b3.y*xv.w;
    m.z = b0.z*xv.x + b1.z*xv.y + b2.z*xv.z + b3.z*xv.w;
    m.w = b0.w*xv.x + b1.w*xv.y + b2.w*xv.z + b3.w*xv.w;

    float* dst = atx + (long long)(blockIdx.x & (nrep - 1)) * n4 + (long long)c * 4;
    unsafeAtomicAdd(dst + 0, m.x);
    unsafeAtomicAdd(dst + 1, m.y);
    unsafeAtomicAdd(dst + 2, m.z);
    unsafeAtomicAdd(dst + 3, m.w);
}

// Mid pass: v = (sum_k ATx_rep[k]) * diag * mask  (written into replica 0);
// out = EPSILON * x * diag.
__global__ void __launch_bounds__(256) mid_kernel(
    const float4* __restrict__ x4,
    const float4* __restrict__ d4,
    const float* __restrict__ mask,
    float4* __restrict__ atx,         // K replicas, stride N float4s
    float4* __restrict__ out4,
    int K, int N)
{
    int n = blockIdx.x * blockDim.x + threadIdx.x;
    if (n >= N) return;

    float4 acc = atx[n];
    for (int k = 1; k < K; ++k) {
        float4 t = atx[(size_t)k * N + n];
        acc.x += t.x; acc.y += t.y; acc.z += t.z; acc.w += t.w;
    }
    float mq = mask[n];
    float4 dv = d4[n];
    acc.x *= dv.x * mq; acc.y *= dv.y * mq;
    acc.z *= dv.z * mq; acc.w *= dv.w * mq;
    atx[n] = acc;                     // replica 0 becomes v

    float4 xv = x4[n];
    float4 o;
    o.x = EPSILON * xv.x * dv.x; o.y = EPSILON * xv.y * dv.y;
    o.z = EPSILON * xv.z * dv.z; o.w = EPSILON * xv.w * dv.w;
    out4[n] = o;
}

// Pass 2: msg[i] = dot(B[e][i][:], v[col[e]]) * mask[row[e]]; atomic-add into
// the blockIdx%K replica of the output accumulator at row[e].
__global__ void __launch_bounds__(256) spmv_kernel(
    const float4* __restrict__ boo,
    const int* __restrict__ row,
    const int* __restrict__ col,
    const float4* __restrict__ v4,    // scaled ATx (replica 0 region)
    const float* __restrict__ mask,
    float* __restrict__ dst,          // K replicas (or out directly if K==0 path)
    long long n4,
    int nrep,
    long long E)
{
    long long e = (long long)blockIdx.x * blockDim.x + threadIdx.x;
    if (e >= E) return;

    const float4* B = boo + e * 4;
    float4 b0 = B[0], b1 = B[1], b2 = B[2], b3 = B[3];
    int c = col[e];
    float4 v = v4[c];
    int r = row[e];
    float mr = mask[r];

    float m0 = (b0.x*v.x + b0.y*v.y + b0.z*v.z + b0.w*v.w) * mr;
    float m1 = (b1.x*v.x + b1.y*v.y + b1.z*v.z + b1.w*v.w) * mr;
    float m2 = (b2.x*v.x + b2.y*v.y + b2.z*v.z + b2.w*v.w) * mr;
    float m3 = (b3.x*v.x + b3.y*v.y + b3.z*v.z + b3.w*v.w) * mr;

    float* d = dst + (long long)(blockIdx.x & (nrep - 1)) * n4 + (long long)r * 4;
    unsafeAtomicAdd(d + 0, m0);
    unsafeAtomicAdd(d + 1, m1);
    unsafeAtomicAdd(d + 2, m2);
    unsafeAtomicAdd(d + 3, m3);
}

// Final: out += sum_k out_rep[k]   (out already holds eps*x*diag from mid).
__global__ void __launch_bounds__(256) fin_kernel(
    const float4* __restrict__ rep,   // K replicas, stride N float4s
    float4* __restrict__ out4,
    int K, int N)
{
    int n = blockIdx.x * blockDim.x + threadIdx.x;
    if (n >= N) return;
    float4 acc = out4[n];
    for (int k = 0; k < K; ++k) {
        float4 t = rep[(size_t)k * N + n];
        acc.x += t.x; acc.y += t.y; acc.z += t.z; acc.w += t.w;
    }
    out4[n] = acc;
}

extern "C" void kernel_launch(void* const* d_in, const int* in_sizes, int n_in,
                              void* d_out, int out_size, void* d_ws, size_t ws_size,
                              hipStream_t stream) {
    const float* x    = (const float*)d_in[0];
    const int*   ei   = (const int*)d_in[1];
    const float* boo  = (const float*)d_in[2];
    const float* mask = (const float*)d_in[3];
    const float* diag = (const float*)d_in[4];
    float* out = (float*)d_out;

    int N = in_sizes[0] / 4;
    long long E = in_sizes[1] / 2;
    const int* row = ei;
    const int* col = ei + E;

    size_t perB = (size_t)N * 4 * sizeof(float);   // one replica, bytes
    long long n4 = (long long)N * 4;

    // Largest power-of-2 replica count K with 2*K replicas fitting in ws.
    int K = 0;
    for (int k = 8; k >= 1; k >>= 1) {
        if (ws_size >= (size_t)(2 * k) * perB) { K = k; break; }
    }

    float* atx = (float*)d_ws;
    const int blk = 256;
    int gEdge = (int)((E + blk - 1) / blk);
    int gNode = (N + blk - 1) / blk;

    if (K >= 1) {
        float* orep = atx + (size_t)K * n4;
        // zero both replica banks (ws is poisoned before every launch)
        hipMemsetAsync(atx, 0, (size_t)(2 * K) * perB, stream);

        spmvt_kernel<<<gEdge, blk, 0, stream>>>(
            (const float4*)boo, row, col, (const float4*)x, atx, n4, K, E);
        mid_kernel<<<gNode, blk, 0, stream>>>(
            (const float4*)x, (const float4*)diag, mask,
            (float4*)atx, (float4*)out, K, N);
        spmv_kernel<<<gEdge, blk, 0, stream>>>(
            (const float4*)boo, row, col, (const float4*)atx, mask, orep, n4, K, E);
        fin_kernel<<<gNode, blk, 0, stream>>>(
            (const float4*)orep, (float4*)out, K, N);
    } else {
        // Fallback (tiny workspace): single accumulator, atomics straight into out.
        hipMemsetAsync(atx, 0, perB, stream);
        spmvt_kernel<<<gEdge, blk, 0, stream>>>(
            (const float4*)boo, row, col, (const float4*)x, atx, n4, 1, E);
        mid_kernel<<<gNode, blk, 0, stream>>>(
            (const float4*)x, (const float4*)diag, mask,
            (float4*)atx, (float4*)out, 1, N);
        spmv_kernel<<<gEdge, blk, 0, stream>>>(
            (const float4*)boo, row, col, (const float4*)atx, mask, out, n4, 1, E);
    }
}